// Round 5
// baseline (907.427 us; speedup 1.0000x reference)
//
#include <hip/hip_runtime.h>

#define C_ 256
#define HW_ 65536
#define IMG_ (C_*HW_)

typedef __attribute__((ext_vector_type(4))) float f32x4;
typedef __attribute__((ext_vector_type(8))) short s16x8;
typedef unsigned long long ull;

__device__ __forceinline__ ushort f2bf(float f) {
  union { float f; unsigned u; } v; v.f = f;
  unsigned u = v.u;
  return (ushort)((u + 0x7fffu + ((u >> 16) & 1u)) >> 16);
}

__device__ __forceinline__ s16x8 ldfrag(const ushort* p) {
  s16x8 v;
  ((ull*)&v)[0] = *(const ull*)(p);
  ((ull*)&v)[1] = *(const ull*)(p + 4);
  return v;
}

__device__ __forceinline__ void st8(ushort* d, uint4 u) {
  *(ull*)(d)     = ((ull*)&u)[0];
  *(ull*)(d + 4) = ((ull*)&u)[1];
}

// ---------------- per-plane stats ----------------
__global__ void k_stats1(const float* __restrict__ x, float2* __restrict__ part) {
  int bid = blockIdx.x;                  // 1024 = (b,c) planes
  int tid = threadIdx.x;
  const f32x4* p = (const f32x4*)(x + (size_t)bid*65536);
  float s = 0.f, ss = 0.f;
  #pragma unroll 4
  for (int i = tid; i < 16384; i += 256) {
    f32x4 v = p[i];
    s  += v[0]+v[1]+v[2]+v[3];
    ss += v[0]*v[0]+v[1]*v[1]+v[2]*v[2]+v[3]*v[3];
  }
  __shared__ float sa[256], sb[256];
  sa[tid]=s; sb[tid]=ss; __syncthreads();
  for (int k=128;k>0;k>>=1){
    if (tid<k){ sa[tid]+=sa[tid+k]; sb[tid]+=sb[tid+k]; }
    __syncthreads();
  }
  if (tid==0) part[bid] = make_float2(sa[0], sb[0]);
}

// ---------------- fold GN stats into per-batch bf16 weights + emit stats ----------------
__global__ void k_fold(const float* __restrict__ wq, const float* __restrict__ bq,
                       const float* __restrict__ wk, const float* __restrict__ bk,
                       const float* __restrict__ wv, const float* __restrict__ bv,
                       const float* __restrict__ wo, const float* __restrict__ bo,
                       const float* __restrict__ gamma, const float* __restrict__ beta,
                       const float2* __restrict__ part,
                       ushort* __restrict__ wAll, ushort* __restrict__ woE,
                       float* __restrict__ biasAll, float2* __restrict__ statsOut) {
  int id = blockIdx.x, co = threadIdx.x;
  if (id == 12) {
    for (int c4 = 0; c4 < 64; ++c4) {
      ushort4 pk;
      pk.x = f2bf(wo[co*256 + c4*4 + 0]);
      pk.y = f2bf(wo[co*256 + c4*4 + 1]);
      pk.z = f2bf(wo[co*256 + c4*4 + 2]);
      pk.w = f2bf(wo[co*256 + c4*4 + 3]);
      *(ushort4*)&woE[co*256 + c4*4] = pk;
    }
    biasAll[3072 + co] = bo[co];
    return;
  }
  int m = id >> 2, b = id & 3;
  __shared__ float mean_s[32], rstd_s[32];
  __shared__ float aS[256], cS[256];
  if (co < 32) {
    float s = 0.f, ss = 0.f;
    for (int j = 0; j < 8; ++j) { float2 v = part[b*256 + co*8 + j]; s += v.x; ss += v.y; }
    float mean = s * (1.f/524288.f);
    float var  = ss * (1.f/524288.f) - mean*mean;
    mean_s[co] = mean; rstd_s[co] = rsqrtf(var + 1e-6f);
  }
  __syncthreads();
  if (m == 0 && co < 32) statsOut[b*32 + co] = make_float2(mean_s[co], rstd_s[co]);
  { int g2 = co >> 3; float a = rstd_s[g2]*gamma[co]; aS[co] = a; cS[co] = beta[co] - mean_s[g2]*a; }
  __syncthreads();
  const float* W  = m==0 ? wq : m==1 ? wk : wv;
  const float* bi = m==0 ? bq : m==1 ? bk : bv;
  float s = (m==0) ? 0.0625f : 1.0f;
  float acc = bi[co];
  ushort* dst = wAll + ((size_t)(m*4 + b)*256 + co)*256;
  for (int c4 = 0; c4 < 64; ++c4) {
    ushort4 pk; float wv_;
    wv_ = W[co*256 + c4*4 + 0]; acc += wv_*cS[c4*4+0]; pk.x = f2bf(wv_*aS[c4*4+0]*s);
    wv_ = W[co*256 + c4*4 + 1]; acc += wv_*cS[c4*4+1]; pk.y = f2bf(wv_*aS[c4*4+1]*s);
    wv_ = W[co*256 + c4*4 + 2]; acc += wv_*cS[c4*4+2]; pk.z = f2bf(wv_*aS[c4*4+2]*s);
    wv_ = W[co*256 + c4*4 + 3]; acc += wv_*cS[c4*4+3]; pk.w = f2bf(wv_*aS[c4*4+3]*s);
    *(ushort4*)&dst[c4*4] = pk;
  }
  biasAll[m*1024 + b*256 + co] = acc * s;
}

// ---------------- GN-normalize + bf16 + window transpose: x -> xnT[win][t][c] ----------------
__global__ __launch_bounds__(256) void k_xt(const float* __restrict__ x,
    const float2* __restrict__ stats, ushort* __restrict__ xnT) {
  int g = blockIdx.x;
  int win = (g & 7)*128 + (g >> 3);
  int b = win >> 8, wy = (win >> 4) & 15, wx = win & 15;
  int tid = threadIdx.x;
  const float* xw = x + (size_t)b*IMG_ + wy*16*256 + wx*16;
  ushort* outp = xnT + (size_t)win*65536;
  __shared__ __align__(16) ushort tile[64*260];
  for (int cc = 0; cc < 4; ++cc) {
    int cbase = cc*64;
    __syncthreads();
    // stage converted chunk [64 ci][256 t] natural layout (wide writes)
    #pragma unroll
    for (int r = 0; r < 16; ++r) {
      int task = tid + 256*r;
      int cl = task >> 6, t4 = task & 63;
      int t = t4*4;
      int ci = cbase + cl;
      f32x4 v = *(const f32x4*)(xw + (size_t)ci*HW_ + (t >> 4)*256 + (t & 15));
      float2 st = stats[b*32 + (ci >> 3)];
      unsigned p0 = (unsigned)f2bf((v[0]-st.x)*st.y) | ((unsigned)f2bf((v[1]-st.x)*st.y) << 16);
      unsigned p1 = (unsigned)f2bf((v[2]-st.x)*st.y) | ((unsigned)f2bf((v[3]-st.x)*st.y) << 16);
      ull pk = (ull)p0 | ((ull)p1 << 32);
      *(ull*)&tile[cl*260 + t] = pk;
    }
    __syncthreads();
    // transposed readout: thread handles rows (2pr, 2pr+1), ci half `sub` (full 64B sectors)
    int pr = tid & 127, sub = tid >> 7;
    int t0 = 2*pr;
    const unsigned* tw = (const unsigned*)tile;
    unsigned lo[16], hi[16];
    #pragma unroll
    for (int k = 0; k < 16; ++k) {
      unsigned a  = tw[(sub*32 + 2*k    )*130 + pr];
      unsigned b2 = tw[(sub*32 + 2*k + 1)*130 + pr];
      lo[k] = (a & 0xffffu) | (b2 << 16);
      hi[k] = (a >> 16) | (b2 & 0xffff0000u);
    }
    ushort* o0 = outp + (size_t)t0*256 + cbase + sub*32;
    ushort* o1 = o0 + 256;
    *(uint4*)(o0)      = *(uint4*)&lo[0];
    *(uint4*)(o0 + 8)  = *(uint4*)&lo[4];
    *(uint4*)(o0 + 16) = *(uint4*)&lo[8];
    *(uint4*)(o0 + 24) = *(uint4*)&lo[12];
    *(uint4*)(o1)      = *(uint4*)&hi[0];
    *(uint4*)(o1 + 8)  = *(uint4*)&hi[4];
    *(uint4*)(o1 + 16) = *(uint4*)&hi[8];
    *(uint4*)(o1 + 24) = *(uint4*)&hi[12];
  }
}

// ---------------- projection GEMM (dbuf LDS + early global loads) ----------------
// phase 0: mats Q (->Qt [t][c]) and V (->V [c][t]);  phase 1: mat K (xnT -> Kt IN PLACE)
__global__ __launch_bounds__(256, 2) void k_proj(const ushort* __restrict__ xnT,
    const ushort* __restrict__ wAll, const float* __restrict__ biasAll,
    ushort* __restrict__ Qt, ushort* __restrict__ Kt, ushort* __restrict__ V,
    int phase) {
  int g = blockIdx.x;
  int xcd = g & 7, i = g >> 3;
  int win, mat, th;
  if (phase == 0) { win = xcd*128 + (i >> 2); mat = (i & 2) ? 2 : 0; th = i & 1; }
  else            { win = xcd*128 + (i >> 1); mat = 1; th = i & 1; }
  int b = win >> 8;
  int tid = threadIdx.x, l = tid & 63, wid = tid >> 6, h = l >> 4;
  int t0 = th * 128;

  // LDS: X(cur) @ cur*13824, W(cur) @ 4608 + cur*13824  (u16 units), total 55296 B
  __shared__ __align__(16) ushort smem[27648];

  const ushort* wsrc = wAll + (size_t)(mat*4 + b)*65536;
  const ushort* xsrc = xnT + (size_t)win*65536 + (size_t)t0*256;

  int xrow = tid >> 1, xhalf = tid & 1;
  const ushort* xg = xsrc + (size_t)xrow*256 + xhalf*16;
  const ushort* wg = wsrc + (size_t)tid*256;

  f32x4 acc[4][8];
  #pragma unroll
  for (int a = 0; a < 4; ++a)
    #pragma unroll
    for (int n = 0; n < 8; ++n) acc[a][n] = (f32x4){0.f,0.f,0.f,0.f};

  int aoff = (mat < 2) ? 0 : 4608;
  int boff = (mat < 2) ? 4608 : 0;
  int arb = (mat < 2) ? (wid & 1)*64 : wid*64;
  int brb = (mat < 2) ? (wid >> 1)*128 : 0;

  uint4 rx[2], rw[4];
  // prologue: load ck=0, stage into buf0
  rx[0] = *(const uint4*)(xg);      rx[1] = *(const uint4*)(xg + 8);
  rw[0] = *(const uint4*)(wg);      rw[1] = *(const uint4*)(wg + 8);
  rw[2] = *(const uint4*)(wg + 16); rw[3] = *(const uint4*)(wg + 24);
  {
    ushort* xd = smem + xrow*36 + xhalf*16;
    st8(xd, rx[0]); st8(xd + 8, rx[1]);
    ushort* wd = smem + 4608 + tid*36;
    st8(wd, rw[0]); st8(wd + 8, rw[1]); st8(wd + 16, rw[2]); st8(wd + 24, rw[3]);
  }
  __syncthreads();

  int cur = 0;
  for (int ck = 0; ck < 8; ++ck) {
    if (ck < 7) {
      const ushort* xp = xg + (ck + 1)*32;
      rx[0] = *(const uint4*)(xp);      rx[1] = *(const uint4*)(xp + 8);
      const ushort* wp = wg + (ck + 1)*32;
      rw[0] = *(const uint4*)(wp);      rw[1] = *(const uint4*)(wp + 8);
      rw[2] = *(const uint4*)(wp + 16); rw[3] = *(const uint4*)(wp + 24);
    }
    const ushort* ab = smem + cur*13824 + aoff;
    const ushort* bb = smem + cur*13824 + boff;
    s16x8 af[4], bf[8];
    #pragma unroll
    for (int ms = 0; ms < 4; ++ms)
      af[ms] = ldfrag(ab + (size_t)(arb + ms*16 + (l & 15))*36 + h*8);
    #pragma unroll
    for (int ns = 0; ns < 8; ++ns)
      bf[ns] = ldfrag(bb + (size_t)(brb + ns*16 + (l & 15))*36 + h*8);
    #pragma unroll
    for (int ms = 0; ms < 4; ++ms)
      #pragma unroll
      for (int ns = 0; ns < 8; ++ns)
        acc[ms][ns] = __builtin_amdgcn_mfma_f32_16x16x32_bf16(af[ms], bf[ns], acc[ms][ns], 0,0,0);
    if (ck < 7) {
      ushort* xd = smem + (cur^1)*13824 + xrow*36 + xhalf*16;
      st8(xd, rx[0]); st8(xd + 8, rx[1]);
      ushort* wd = smem + (cur^1)*13824 + 4608 + tid*36;
      st8(wd, rw[0]); st8(wd + 8, rw[1]); st8(wd + 16, rw[2]); st8(wd + 24, rw[3]);
    }
    __syncthreads();
    cur ^= 1;
  }

  // ---- epilogue via LDS slab -> wide stores (all acc indices compile-time) ----
  if (mat < 2) {
    ushort* dst = ((mat == 0) ? Qt : Kt) + (size_t)win*65536;
    float bc[8];
    #pragma unroll
    for (int ns = 0; ns < 8; ++ns)
      bc[ns] = biasAll[mat*1024 + b*256 + brb + ns*16 + (l & 15)];
    #pragma unroll
    for (int sl = 0; sl < 4; ++sl) {
      __syncthreads();
      if ((wid >> 1) == (sl >> 1)) {
        const int nsb = (sl & 1)*4;
        #pragma unroll
        for (int ms = 0; ms < 4; ++ms)
          #pragma unroll
          for (int k = 0; k < 4; ++k)
            #pragma unroll
            for (int j = 0; j < 4; ++j) {
              int row = (wid & 1)*64 + ms*16 + 4*h + j;
              smem[row*68 + k*16 + (l & 15)] = f2bf(acc[ms][nsb + k][j] + bc[nsb + k]);
            }
      }
      __syncthreads();
      #pragma unroll
      for (int p = 0; p < 4; ++p) {
        int rr = p*32 + (tid >> 3), seg = tid & 7;
        const ushort* sp = &smem[rr*68 + seg*8];
        uint4 v;
        ((ull*)&v)[0] = *(const ull*)sp;
        ((ull*)&v)[1] = *(const ull*)(sp + 4);
        *(uint4*)(dst + (size_t)(t0 + rr)*256 + sl*64 + seg*8) = v;
      }
    }
  } else {
    ushort* dst = V + (size_t)win*65536;
    f32x4 br[4];
    #pragma unroll
    for (int ms = 0; ms < 4; ++ms)
      br[ms] = *(const f32x4*)&biasAll[2048 + b*256 + wid*64 + ms*16 + 4*h];
    #pragma unroll
    for (int sl = 0; sl < 2; ++sl) {
      __syncthreads();
      {
        const int nsb = sl*4;
        #pragma unroll
        for (int ms = 0; ms < 4; ++ms)
          #pragma unroll
          for (int k = 0; k < 4; ++k)
            #pragma unroll
            for (int j = 0; j < 4; ++j) {
              int row = wid*64 + ms*16 + 4*h + j;
              smem[row*68 + k*16 + (l & 15)] = f2bf(acc[ms][nsb + k][j] + br[ms][j]);
            }
      }
      __syncthreads();
      #pragma unroll
      for (int p = 0; p < 8; ++p) {
        int rr = p*32 + (tid >> 3), seg = tid & 7;
        const ushort* sp = &smem[rr*68 + seg*8];
        uint4 v;
        ((ull*)&v)[0] = *(const ull*)sp;
        ((ull*)&v)[1] = *(const ull*)(sp + 4);
        *(uint4*)(dst + (size_t)rr*256 + t0 + sl*64 + seg*8) = v;
      }
    }
  }
}

// ---------------- windowed attention (T14 register-prefetch staging) ----------------
__global__ __launch_bounds__(256, 2) void k_attn(const ushort* __restrict__ Qt,
    const ushort* __restrict__ Kt, const ushort* __restrict__ V,
    ushort* __restrict__ AO) {
  int g = blockIdx.x;
  int xcd = g & 7, i = g >> 3;
  int w = xcd*128 + (i >> 2), qt = i & 3;
  int q0 = qt * 64;
  int tid = threadIdx.x, l = tid & 63, wid = tid >> 6, h = l >> 4;
  __shared__ __align__(16) ushort Aq[64*36];
  __shared__ __align__(16) ushort BKV[256*36];
  __shared__ __align__(16) ushort P[64*276];
  __shared__ float red[2][4][64];
  const ushort* qbase = Qt + (size_t)w*65536;
  const ushort* kbase = Kt + (size_t)w*65536;
  const ushort* vbase = V  + (size_t)w*65536;
  int nbase = wid * 64;
  int qrow = tid >> 2, qseg = tid & 3;

  f32x4 accS[4][4];
  #pragma unroll
  for (int a=0;a<4;a++)
    #pragma unroll
    for (int n=0;n<4;n++) accS[a][n] = (f32x4){0.f,0.f,0.f,0.f};

  // prologue: stage ck=0
  uint4 rq, rk0, rk1, rk2, rk3;
  rq  = *(const uint4*)(qbase + (size_t)(q0 + qrow)*256 + qseg*8);
  { const ushort* kr = kbase + (size_t)tid*256;
    rk0 = *(const uint4*)(kr);      rk1 = *(const uint4*)(kr + 8);
    rk2 = *(const uint4*)(kr + 16); rk3 = *(const uint4*)(kr + 24); }
  st8(&Aq[qrow*36 + qseg*8], rq);
  st8(&BKV[tid*36],      rk0);
  st8(&BKV[tid*36 + 8],  rk1);
  st8(&BKV[tid*36 + 16], rk2);
  st8(&BKV[tid*36 + 24], rk3);
  __syncthreads();

  uint4 rv0, rv1, rv2, rv3;
  for (int ck = 0; ck < 8; ++ck) {
    if (ck < 7) {
      int cb = (ck + 1)*32;
      rq = *(const uint4*)(qbase + (size_t)(q0 + qrow)*256 + cb + qseg*8);
      const ushort* kp = kbase + (size_t)tid*256 + cb;
      rk0 = *(const uint4*)(kp);      rk1 = *(const uint4*)(kp + 8);
      rk2 = *(const uint4*)(kp + 16); rk3 = *(const uint4*)(kp + 24);
    } else {
      // pre-issue V(kt=0): softmax phase hides its latency
      const ushort* vr = vbase + (size_t)tid*256;
      rv0 = *(const uint4*)(vr);      rv1 = *(const uint4*)(vr + 8);
      rv2 = *(const uint4*)(vr + 16); rv3 = *(const uint4*)(vr + 24);
    }
    s16x8 af[4];
    #pragma unroll
    for (int ms = 0; ms < 4; ++ms)
      af[ms] = ldfrag(&Aq[(ms*16 + (l & 15))*36 + h*8]);
    #pragma unroll
    for (int ns = 0; ns < 4; ++ns) {
      s16x8 bf = ldfrag(&BKV[(nbase + ns*16 + (l & 15))*36 + h*8]);
      #pragma unroll
      for (int ms = 0; ms < 4; ++ms)
        accS[ms][ns] = __builtin_amdgcn_mfma_f32_16x16x32_bf16(af[ms], bf, accS[ms][ns], 0,0,0);
    }
    __syncthreads();
    if (ck < 7) {
      st8(&Aq[qrow*36 + qseg*8], rq);
      st8(&BKV[tid*36],      rk0);
      st8(&BKV[tid*36 + 8],  rk1);
      st8(&BKV[tid*36 + 16], rk2);
      st8(&BKV[tid*36 + 24], rk3);
      __syncthreads();
    }
  }

  // softmax over k
  float mx[4][4];
  #pragma unroll
  for (int ms=0;ms<4;ms++)
    #pragma unroll
    for (int j=0;j<4;j++) {
      float m_ = fmaxf(fmaxf(accS[ms][0][j], accS[ms][1][j]),
                       fmaxf(accS[ms][2][j], accS[ms][3][j]));
      #pragma unroll
      for (int msk=1; msk<16; msk<<=1) m_ = fmaxf(m_, __shfl_xor(m_, msk));
      mx[ms][j] = m_;
    }
  if ((l & 15) == 0) {
    #pragma unroll
    for (int ms=0;ms<4;ms++)
      #pragma unroll
      for (int j=0;j<4;j++) red[0][wid][ms*16 + 4*h + j] = mx[ms][j];
  }
  __syncthreads();
  // all K reads retired at this point -> stage V(kt=0) into BKV
  st8(&BKV[tid*36],      rv0);
  st8(&BKV[tid*36 + 8],  rv1);
  st8(&BKV[tid*36 + 16], rv2);
  st8(&BKV[tid*36 + 24], rv3);
  float sj[4][4];
  #pragma unroll
  for (int ms=0;ms<4;ms++)
    #pragma unroll
    for (int j=0;j<4;j++) {
      int row = ms*16 + 4*h + j;
      float gm = fmaxf(fmaxf(red[0][0][row], red[0][1][row]),
                       fmaxf(red[0][2][row], red[0][3][row]));
      float s_ = 0.f;
      #pragma unroll
      for (int ns=0;ns<4;ns++) {
        float p = __expf(accS[ms][ns][j] - gm);
        accS[ms][ns][j] = p;
        s_ += p;
      }
      #pragma unroll
      for (int msk=1; msk<16; msk<<=1) s_ += __shfl_xor(s_, msk);
      sj[ms][j] = s_;
    }
  if ((l & 15) == 0) {
    #pragma unroll
    for (int ms=0;ms<4;ms++)
      #pragma unroll
      for (int j=0;j<4;j++) red[1][wid][ms*16 + 4*h + j] = sj[ms][j];
  }
  __syncthreads();
  float rinv[4][4];
  #pragma unroll
  for (int ms=0;ms<4;ms++)
    #pragma unroll
    for (int j=0;j<4;j++) {
      int row = ms*16 + 4*h + j;
      rinv[ms][j] = 1.f / (red[1][0][row]+red[1][1][row]+red[1][2][row]+red[1][3][row]);
    }
  #pragma unroll
  for (int ms=0;ms<4;ms++)
    #pragma unroll
    for (int j=0;j<4;j++)
      #pragma unroll
      for (int ns=0;ns<4;ns++)
        P[(ms*16 + 4*h + j)*276 + nbase + ns*16 + (l & 15)] = f2bf(accS[ms][ns][j]);

  // PV (register-prefetch V chunks)
  f32x4 accO[4][4];
  #pragma unroll
  for (int a=0;a<4;a++)
    #pragma unroll
    for (int n=0;n<4;n++) accO[a][n] = (f32x4){0.f,0.f,0.f,0.f};

  __syncthreads();   // P + V0 visible
  for (int kt = 0; kt < 8; ++kt) {
    if (kt < 7) {
      const ushort* vr = vbase + (size_t)tid*256 + (kt + 1)*32;
      rv0 = *(const uint4*)(vr);      rv1 = *(const uint4*)(vr + 8);
      rv2 = *(const uint4*)(vr + 16); rv3 = *(const uint4*)(vr + 24);
    }
    s16x8 ap[4];
    #pragma unroll
    for (int ms = 0; ms < 4; ++ms)
      ap[ms] = ldfrag(&P[(ms*16 + (l & 15))*276 + kt*32 + h*8]);
    #pragma unroll
    for (int ns = 0; ns < 4; ++ns) {
      s16x8 bf = ldfrag(&BKV[(nbase + ns*16 + (l & 15))*36 + h*8]);
      #pragma unroll
      for (int ms = 0; ms < 4; ++ms)
        accO[ms][ns] = __builtin_amdgcn_mfma_f32_16x16x32_bf16(ap[ms], bf, accO[ms][ns], 0,0,0);
    }
    __syncthreads();
    if (kt < 7) {
      st8(&BKV[tid*36],      rv0);
      st8(&BKV[tid*36 + 8],  rv1);
      st8(&BKV[tid*36 + 16], rv2);
      st8(&BKV[tid*36 + 24], rv3);
      __syncthreads();
    }
  }

  // wide AO store via P reuse (last-iter barrier above guarantees P reads done)
  #pragma unroll
  for (int ms=0;ms<4;ms++)
    #pragma unroll
    for (int j=0;j<4;j++) {
      float rv = rinv[ms][j];
      int q = ms*16 + 4*h + j;
      #pragma unroll
      for (int ns=0;ns<4;ns++)
        P[q*276 + nbase + ns*16 + (l & 15)] = f2bf(accO[ms][ns][j] * rv);
    }
  __syncthreads();
  ushort* aob = AO + (size_t)w*65536;
  #pragma unroll
  for (int it = 0; it < 8; ++it) {
    int task = tid + 256*it;
    int r = task >> 5, seg = task & 31;
    const ushort* sp = &P[r*276 + seg*8];
    uint4 v;
    ((ull*)&v)[0] = *(const ull*)sp;
    ((ull*)&v)[1] = *(const ull*)(sp + 4);
    *(uint4*)(aob + (size_t)(q0 + r)*256 + seg*8) = v;
  }
}

// ---------------- output projection + residual (register-prefetch staging) ----------------
__global__ __launch_bounds__(512, 2) void k_oproj(const float* __restrict__ x,
    const ushort* __restrict__ AO, const ushort* __restrict__ woE,
    const float* __restrict__ biasAll, float* __restrict__ y) {
  int g = blockIdx.x;
  int w = (g & 7)*128 + (g >> 3);
  int b = w >> 8, wy = (w >> 4) & 15, wx = w & 15;
  int tid = threadIdx.x, l = tid & 63, wid = tid >> 6, h = l >> 4;
  __shared__ __align__(16) ushort alds[256*36];
  __shared__ __align__(16) ushort wlds[256*36];
  const ushort* abase = AO + (size_t)w*65536;

  f32x4 acc[8][4];
  #pragma unroll
  for (int a=0;a<8;a++)
    #pragma unroll
    for (int n=0;n<4;n++) acc[a][n] = (f32x4){0.f,0.f,0.f,0.f};
  int mbase = (wid >> 2)*128, nbase = (wid & 3)*64;

  int orow = tid >> 1, oseg = (tid & 1)*16;   // 32B per thread, contiguous
  const ushort* wg0 = woE + (size_t)orow*256 + oseg;
  const ushort* ag0 = abase + (size_t)orow*256 + oseg;
  ushort* wd = &wlds[orow*36 + oseg];
  ushort* ad = &alds[orow*36 + oseg];

  uint4 rw0, rw1, ra0, ra1;
  rw0 = *(const uint4*)(wg0);     rw1 = *(const uint4*)(wg0 + 8);
  ra0 = *(const uint4*)(ag0);     ra1 = *(const uint4*)(ag0 + 8);
  st8(wd, rw0); st8(wd + 8, rw1);
  st8(ad, ra0); st8(ad + 8, ra1);
  __syncthreads();

  for (int ck = 0; ck < 8; ++ck) {
    if (ck < 7) {
      const ushort* wp = wg0 + (ck + 1)*32;
      const ushort* ap2 = ag0 + (ck + 1)*32;
      rw0 = *(const uint4*)(wp);   rw1 = *(const uint4*)(wp + 8);
      ra0 = *(const uint4*)(ap2);  ra1 = *(const uint4*)(ap2 + 8);
    }
    s16x8 bf[4];
    #pragma unroll
    for (int ns = 0; ns < 4; ++ns)
      bf[ns] = ldfrag(&alds[(nbase + ns*16 + (l & 15))*36 + h*8]);
    #pragma unroll
    for (int ms = 0; ms < 8; ++ms) {
      s16x8 af = ldfrag(&wlds[(mbase + ms*16 + (l & 15))*36 + h*8]);
      #pragma unroll
      for (int ns = 0; ns < 4; ++ns)
        acc[ms][ns] = __builtin_amdgcn_mfma_f32_16x16x32_bf16(af, bf[ns], acc[ms][ns], 0,0,0);
    }
    __syncthreads();
    if (ck < 7) {
      st8(wd, rw0); st8(wd + 8, rw1);
      st8(ad, ra0); st8(ad + 8, ra1);
      __syncthreads();
    }
  }
  const float* bs = biasAll + 3072;
  const float* xbase = x + (size_t)b*IMG_ + wy*16*256 + wx*16;
  float* ybase = y + (size_t)b*IMG_ + wy*16*256 + wx*16;
  #pragma unroll
  for (int ms = 0; ms < 8; ++ms) {
    f32x4 b4 = *(const f32x4*)&bs[mbase + ms*16 + 4*h];
    #pragma unroll
    for (int j = 0; j < 4; ++j) {
      int o = mbase + ms*16 + 4*h + j;
      #pragma unroll
      for (int ns = 0; ns < 4; ++ns) {
        int t = nbase + ns*16 + (l & 15);
        size_t off = (size_t)o*HW_ + (t >> 4)*256 + (t & 15);
        ybase[off] = xbase[off] + acc[ms][ns][j] + b4[j];
      }
    }
  }
}

extern "C" void kernel_launch(void* const* d_in, const int* in_sizes, int n_in,
                              void* d_out, int out_size, void* d_ws, size_t ws_size,
                              hipStream_t stream) {
  const float* x     = (const float*)d_in[0];
  const float* gamma = (const float*)d_in[1];
  const float* beta  = (const float*)d_in[2];
  const float* wq = (const float*)d_in[3];
  const float* bq = (const float*)d_in[4];
  const float* wk = (const float*)d_in[5];
  const float* bk = (const float*)d_in[6];
  const float* wv = (const float*)d_in[7];
  const float* bv = (const float*)d_in[8];
  const float* wo = (const float*)d_in[9];
  const float* bo = (const float*)d_in[10];
  float* y = (float*)d_out;
  char* ws = (char*)d_ws;

  float2* part    = (float2*)ws;                        // 8 KB
  float*  biasAll = (float*)(ws + 8192);                // 13.3 KB
  float2* stats   = (float2*)(ws + 24576);              // 1 KB
  ushort* wAll    = (ushort*)(ws + 32768);              // 1.5 MB
  ushort* woE     = (ushort*)(ws + 32768 + 1572864);    // 128 KB
  ushort* Qt      = (ushort*)(ws + 2097152);            // 134 MB (also AO)
  // d_out: xnT (then Kt IN PLACE) @0, V @+134MB; fully overwritten by k_oproj at the end
  ushort* xnT = (ushort*)d_out;
  ushort* Kt  = (ushort*)d_out;
  ushort* V   = (ushort*)d_out + (size_t)67108864;

  k_stats1<<<1024, 256, 0, stream>>>(x, part);
  k_fold<<<13, 256, 0, stream>>>(wq,bq,wk,bk,wv,bv,wo,bo,gamma,beta,part,wAll,woE,biasAll,stats);
  k_xt<<<1024, 256, 0, stream>>>(x, stats, xnT);
  k_proj<<<4096, 256, 0, stream>>>(xnT, wAll, biasAll, Qt, Kt, V, 0);  // Q, V
  k_proj<<<2048, 256, 0, stream>>>(xnT, wAll, biasAll, Qt, Kt, V, 1);  // K (in place)
  k_attn<<<4096, 256, 0, stream>>>(Qt, Kt, V, Qt /*AO alias: disjoint rows*/);
  k_oproj<<<1024, 512, 0, stream>>>(x, Qt /*AO*/, woE, biasAll, y);
}

// Round 7
// 879.365 us; speedup vs baseline: 1.0319x; 1.0319x over previous
//
#include <hip/hip_runtime.h>

#define C_ 256
#define HW_ 65536
#define IMG_ (C_*HW_)

typedef __attribute__((ext_vector_type(4))) float f32x4;
typedef __attribute__((ext_vector_type(8))) short s16x8;
typedef unsigned long long ull;

__device__ __forceinline__ ushort f2bf(float f) {
  union { float f; unsigned u; } v; v.f = f;
  unsigned u = v.u;
  return (ushort)((u + 0x7fffu + ((u >> 16) & 1u)) >> 16);
}

__device__ __forceinline__ s16x8 ldfrag(const ushort* p) {
  s16x8 v;
  ((ull*)&v)[0] = *(const ull*)(p);
  ((ull*)&v)[1] = *(const ull*)(p + 4);
  return v;
}

__device__ __forceinline__ void st8(ushort* d, uint4 u) {
  *(ull*)(d)     = ((ull*)&u)[0];
  *(ull*)(d + 4) = ((ull*)&u)[1];
}

// ---------------- per-plane stats ----------------
__global__ void k_stats1(const float* __restrict__ x, float2* __restrict__ part) {
  int bid = blockIdx.x;                  // 1024 = (b,c) planes
  int tid = threadIdx.x;
  const f32x4* p = (const f32x4*)(x + (size_t)bid*65536);
  float s = 0.f, ss = 0.f;
  #pragma unroll 4
  for (int i = tid; i < 16384; i += 256) {
    f32x4 v = p[i];
    s  += v[0]+v[1]+v[2]+v[3];
    ss += v[0]*v[0]+v[1]*v[1]+v[2]*v[2]+v[3]*v[3];
  }
  __shared__ float sa[256], sb[256];
  sa[tid]=s; sb[tid]=ss; __syncthreads();
  for (int k=128;k>0;k>>=1){
    if (tid<k){ sa[tid]+=sa[tid+k]; sb[tid]+=sb[tid+k]; }
    __syncthreads();
  }
  if (tid==0) part[bid] = make_float2(sa[0], sb[0]);
}

// ---------------- fold GN stats into per-batch bf16 weights + emit stats ----------------
__global__ void k_fold(const float* __restrict__ wq, const float* __restrict__ bq,
                       const float* __restrict__ wk, const float* __restrict__ bk,
                       const float* __restrict__ wv, const float* __restrict__ bv,
                       const float* __restrict__ wo, const float* __restrict__ bo,
                       const float* __restrict__ gamma, const float* __restrict__ beta,
                       const float2* __restrict__ part,
                       ushort* __restrict__ wAll, ushort* __restrict__ woE,
                       float* __restrict__ biasAll, float2* __restrict__ statsOut) {
  int id = blockIdx.x, co = threadIdx.x;
  if (id == 12) {
    for (int c4 = 0; c4 < 64; ++c4) {
      ushort4 pk;
      pk.x = f2bf(wo[co*256 + c4*4 + 0]);
      pk.y = f2bf(wo[co*256 + c4*4 + 1]);
      pk.z = f2bf(wo[co*256 + c4*4 + 2]);
      pk.w = f2bf(wo[co*256 + c4*4 + 3]);
      *(ushort4*)&woE[co*256 + c4*4] = pk;
    }
    biasAll[3072 + co] = bo[co];
    return;
  }
  int m = id >> 2, b = id & 3;
  __shared__ float mean_s[32], rstd_s[32];
  __shared__ float aS[256], cS[256];
  if (co < 32) {
    float s = 0.f, ss = 0.f;
    for (int j = 0; j < 8; ++j) { float2 v = part[b*256 + co*8 + j]; s += v.x; ss += v.y; }
    float mean = s * (1.f/524288.f);
    float var  = ss * (1.f/524288.f) - mean*mean;
    mean_s[co] = mean; rstd_s[co] = rsqrtf(var + 1e-6f);
  }
  __syncthreads();
  if (m == 0 && co < 32) statsOut[b*32 + co] = make_float2(mean_s[co], rstd_s[co]);
  { int g2 = co >> 3; float a = rstd_s[g2]*gamma[co]; aS[co] = a; cS[co] = beta[co] - mean_s[g2]*a; }
  __syncthreads();
  const float* W  = m==0 ? wq : m==1 ? wk : wv;
  const float* bi = m==0 ? bq : m==1 ? bk : bv;
  float s = (m==0) ? 0.0625f : 1.0f;
  float acc = bi[co];
  ushort* dst = wAll + ((size_t)(m*4 + b)*256 + co)*256;
  for (int c4 = 0; c4 < 64; ++c4) {
    ushort4 pk; float wv_;
    wv_ = W[co*256 + c4*4 + 0]; acc += wv_*cS[c4*4+0]; pk.x = f2bf(wv_*aS[c4*4+0]*s);
    wv_ = W[co*256 + c4*4 + 1]; acc += wv_*cS[c4*4+1]; pk.y = f2bf(wv_*aS[c4*4+1]*s);
    wv_ = W[co*256 + c4*4 + 2]; acc += wv_*cS[c4*4+2]; pk.z = f2bf(wv_*aS[c4*4+2]*s);
    wv_ = W[co*256 + c4*4 + 3]; acc += wv_*cS[c4*4+3]; pk.w = f2bf(wv_*aS[c4*4+3]*s);
    *(ushort4*)&dst[c4*4] = pk;
  }
  biasAll[m*1024 + b*256 + co] = acc * s;
}

// ---------------- GN-normalize + bf16 + window transpose: x -> xnT[win][t][c] ----------------
__global__ __launch_bounds__(256) void k_xt(const float* __restrict__ x,
    const float2* __restrict__ stats, ushort* __restrict__ xnT) {
  int g = blockIdx.x;
  int win = (g & 7)*128 + (g >> 3);
  int b = win >> 8, wy = (win >> 4) & 15, wx = win & 15;
  int tid = threadIdx.x;
  const float* xw = x + (size_t)b*IMG_ + wy*16*256 + wx*16;
  ushort* outp = xnT + (size_t)win*65536;
  __shared__ __align__(16) ushort tile[64*260];
  for (int cc = 0; cc < 4; ++cc) {
    int cbase = cc*64;
    __syncthreads();
    #pragma unroll
    for (int r = 0; r < 16; ++r) {
      int task = tid + 256*r;
      int cl = task >> 6, t4 = task & 63;
      int t = t4*4;
      int ci = cbase + cl;
      f32x4 v = *(const f32x4*)(xw + (size_t)ci*HW_ + (t >> 4)*256 + (t & 15));
      float2 st = stats[b*32 + (ci >> 3)];
      unsigned p0 = (unsigned)f2bf((v[0]-st.x)*st.y) | ((unsigned)f2bf((v[1]-st.x)*st.y) << 16);
      unsigned p1 = (unsigned)f2bf((v[2]-st.x)*st.y) | ((unsigned)f2bf((v[3]-st.x)*st.y) << 16);
      ull pk = (ull)p0 | ((ull)p1 << 32);
      *(ull*)&tile[cl*260 + t] = pk;
    }
    __syncthreads();
    int pr = tid & 127, sub = tid >> 7;
    int t0 = 2*pr;
    const unsigned* tw = (const unsigned*)tile;
    unsigned lo[16], hi[16];
    #pragma unroll
    for (int k = 0; k < 16; ++k) {
      unsigned a  = tw[(sub*32 + 2*k    )*130 + pr];
      unsigned b2 = tw[(sub*32 + 2*k + 1)*130 + pr];
      lo[k] = (a & 0xffffu) | (b2 << 16);
      hi[k] = (a >> 16) | (b2 & 0xffff0000u);
    }
    ushort* o0 = outp + (size_t)t0*256 + cbase + sub*32;
    ushort* o1 = o0 + 256;
    *(uint4*)(o0)      = *(uint4*)&lo[0];
    *(uint4*)(o0 + 8)  = *(uint4*)&lo[4];
    *(uint4*)(o0 + 16) = *(uint4*)&lo[8];
    *(uint4*)(o0 + 24) = *(uint4*)&lo[12];
    *(uint4*)(o1)      = *(uint4*)&hi[0];
    *(uint4*)(o1 + 8)  = *(uint4*)&hi[4];
    *(uint4*)(o1 + 16) = *(uint4*)&hi[8];
    *(uint4*)(o1 + 24) = *(uint4*)&hi[12];
  }
}

// ---------------- projection GEMM (dbuf LDS + early global loads) ----------------
// phase 0: Q,V (th halves); phase 1: K (in place over xnT); phase 2: all 3 mats (Kt separate)
__global__ __launch_bounds__(256, 2) void k_proj(const ushort* __restrict__ xnT,
    const ushort* __restrict__ wAll, const float* __restrict__ biasAll,
    ushort* __restrict__ Qt, ushort* __restrict__ Kt, ushort* __restrict__ V,
    int phase) {
  int g = blockIdx.x;
  int xcd = g & 7, i = g >> 3;
  int win, mat, th;
  if (phase == 2)      { win = xcd*128 + i/6; int r6 = i % 6; mat = r6 >> 1; th = r6 & 1; }
  else if (phase == 0) { win = xcd*128 + (i >> 2); mat = (i & 2) ? 2 : 0; th = i & 1; }
  else                 { win = xcd*128 + (i >> 1); mat = 1; th = i & 1; }
  int b = win >> 8;
  int tid = threadIdx.x, l = tid & 63, wid = tid >> 6, h = l >> 4;
  int t0 = th * 128;

  __shared__ __align__(16) ushort smem[27648];

  const ushort* wsrc = wAll + (size_t)(mat*4 + b)*65536;
  const ushort* xsrc = xnT + (size_t)win*65536 + (size_t)t0*256;

  int xrow = tid >> 1, xhalf = tid & 1;
  const ushort* xg = xsrc + (size_t)xrow*256 + xhalf*16;
  const ushort* wg = wsrc + (size_t)tid*256;

  f32x4 acc[4][8];
  #pragma unroll
  for (int a = 0; a < 4; ++a)
    #pragma unroll
    for (int n = 0; n < 8; ++n) acc[a][n] = (f32x4){0.f,0.f,0.f,0.f};

  int aoff = (mat < 2) ? 0 : 4608;
  int boff = (mat < 2) ? 4608 : 0;
  int arb = (mat < 2) ? (wid & 1)*64 : wid*64;
  int brb = (mat < 2) ? (wid >> 1)*128 : 0;

  uint4 rx[2], rw[4];
  rx[0] = *(const uint4*)(xg);      rx[1] = *(const uint4*)(xg + 8);
  rw[0] = *(const uint4*)(wg);      rw[1] = *(const uint4*)(wg + 8);
  rw[2] = *(const uint4*)(wg + 16); rw[3] = *(const uint4*)(wg + 24);
  {
    ushort* xd = smem + xrow*36 + xhalf*16;
    st8(xd, rx[0]); st8(xd + 8, rx[1]);
    ushort* wd = smem + 4608 + tid*36;
    st8(wd, rw[0]); st8(wd + 8, rw[1]); st8(wd + 16, rw[2]); st8(wd + 24, rw[3]);
  }
  __syncthreads();

  int cur = 0;
  for (int ck = 0; ck < 8; ++ck) {
    if (ck < 7) {
      const ushort* xp = xg + (ck + 1)*32;
      rx[0] = *(const uint4*)(xp);      rx[1] = *(const uint4*)(xp + 8);
      const ushort* wp = wg + (ck + 1)*32;
      rw[0] = *(const uint4*)(wp);      rw[1] = *(const uint4*)(wp + 8);
      rw[2] = *(const uint4*)(wp + 16); rw[3] = *(const uint4*)(wp + 24);
    }
    const ushort* ab = smem + cur*13824 + aoff;
    const ushort* bb = smem + cur*13824 + boff;
    s16x8 af[4], bf[8];
    #pragma unroll
    for (int ms = 0; ms < 4; ++ms)
      af[ms] = ldfrag(ab + (size_t)(arb + ms*16 + (l & 15))*36 + h*8);
    #pragma unroll
    for (int ns = 0; ns < 8; ++ns)
      bf[ns] = ldfrag(bb + (size_t)(brb + ns*16 + (l & 15))*36 + h*8);
    #pragma unroll
    for (int ms = 0; ms < 4; ++ms)
      #pragma unroll
      for (int ns = 0; ns < 8; ++ns)
        acc[ms][ns] = __builtin_amdgcn_mfma_f32_16x16x32_bf16(af[ms], bf[ns], acc[ms][ns], 0,0,0);
    if (ck < 7) {
      ushort* xd = smem + (cur^1)*13824 + xrow*36 + xhalf*16;
      st8(xd, rx[0]); st8(xd + 8, rx[1]);
      ushort* wd = smem + (cur^1)*13824 + 4608 + tid*36;
      st8(wd, rw[0]); st8(wd + 8, rw[1]); st8(wd + 16, rw[2]); st8(wd + 24, rw[3]);
    }
    __syncthreads();
    cur ^= 1;
  }

  if (mat < 2) {
    ushort* dst = ((mat == 0) ? Qt : Kt) + (size_t)win*65536;
    float bc[8];
    #pragma unroll
    for (int ns = 0; ns < 8; ++ns)
      bc[ns] = biasAll[mat*1024 + b*256 + brb + ns*16 + (l & 15)];
    #pragma unroll
    for (int sl = 0; sl < 4; ++sl) {
      __syncthreads();
      if ((wid >> 1) == (sl >> 1)) {
        const int nsb = (sl & 1)*4;
        #pragma unroll
        for (int ms = 0; ms < 4; ++ms)
          #pragma unroll
          for (int k = 0; k < 4; ++k)
            #pragma unroll
            for (int j = 0; j < 4; ++j) {
              int row = (wid & 1)*64 + ms*16 + 4*h + j;
              smem[row*68 + k*16 + (l & 15)] = f2bf(acc[ms][nsb + k][j] + bc[nsb + k]);
            }
      }
      __syncthreads();
      #pragma unroll
      for (int p = 0; p < 4; ++p) {
        int rr = p*32 + (tid >> 3), seg = tid & 7;
        const ushort* sp = &smem[rr*68 + seg*8];
        uint4 v;
        ((ull*)&v)[0] = *(const ull*)sp;
        ((ull*)&v)[1] = *(const ull*)(sp + 4);
        *(uint4*)(dst + (size_t)(t0 + rr)*256 + sl*64 + seg*8) = v;
      }
    }
  } else {
    ushort* dst = V + (size_t)win*65536;
    f32x4 br[4];
    #pragma unroll
    for (int ms = 0; ms < 4; ++ms)
      br[ms] = *(const f32x4*)&biasAll[2048 + b*256 + wid*64 + ms*16 + 4*h];
    #pragma unroll
    for (int sl = 0; sl < 2; ++sl) {
      __syncthreads();
      {
        const int nsb = sl*4;
        #pragma unroll
        for (int ms = 0; ms < 4; ++ms)
          #pragma unroll
          for (int k = 0; k < 4; ++k)
            #pragma unroll
            for (int j = 0; j < 4; ++j) {
              int row = wid*64 + ms*16 + 4*h + j;
              smem[row*68 + k*16 + (l & 15)] = f2bf(acc[ms][nsb + k][j] + br[ms][j]);
            }
      }
      __syncthreads();
      #pragma unroll
      for (int p = 0; p < 8; ++p) {
        int rr = p*32 + (tid >> 3), seg = tid & 7;
        const ushort* sp = &smem[rr*68 + seg*8];
        uint4 v;
        ((ull*)&v)[0] = *(const ull*)sp;
        ((ull*)&v)[1] = *(const ull*)(sp + 4);
        *(uint4*)(dst + (size_t)rr*256 + t0 + sl*64 + seg*8) = v;
      }
    }
  }
}

// ---------------- windowed attention: q-split waves, Q-in-regs, 64-key tiles ----------------
__global__ __launch_bounds__(256, 2) void k_attn(const ushort* __restrict__ Qt,
    const ushort* __restrict__ Kt, const ushort* __restrict__ V,
    ushort* __restrict__ AO) {
  int g = blockIdx.x;
  int i = g >> 3;
  int w = (g & 7)*128 + (i >> 2), qt = i & 3;
  int q0 = qt * 64;
  int tid = threadIdx.x, l = tid & 63, wid = tid >> 6, h = l >> 4, lr = l & 15;
  // KV: K-tile [64][260] (33.3KB) / V-tile [256][68] (34.8KB) / AO slab [64][260]
  __shared__ __align__(16) ushort KV[17408];
  __shared__ __align__(16) ushort Ps[4][1088];   // per-wave P-subtile [16 q][68]
  const ushort* qbase = Qt + (size_t)w*65536;
  const ushort* kbase = Kt + (size_t)w*65536;
  const ushort* vbase = V  + (size_t)w*65536;

  // Q into registers: lane owns q-row (q0 + wid*16 + lr), 8 d-fragments
  s16x8 qf[8];
  {
    const ushort* qp = qbase + (size_t)(q0 + wid*16 + lr)*256 + h*8;
    #pragma unroll
    for (int dk = 0; dk < 8; ++dk) {
      uint4 u = *(const uint4*)(qp + dk*32);
      qf[dk] = *(s16x8*)&u;
    }
  }

  // staging geometry
  int krow = tid >> 2, kseg = (tid & 3)*64;          // K-tile: row 0..63, 128B seg
  const ushort* kg = kbase + (size_t)krow*256 + kseg;
  ushort* kd = &KV[krow*260 + kseg];
  const ushort* vg = vbase + (size_t)tid*256;         // V-tile: c = tid, 64 k-cols
  ushort* vd = &KV[tid*68];

  uint4 rv[8];
  #pragma unroll
  for (int u = 0; u < 8; ++u) rv[u] = *(const uint4*)(kg + u*8);
  #pragma unroll
  for (int u = 0; u < 8; ++u) st8(kd + u*8, rv[u]);
  __syncthreads();

  f32x4 accS[16];
  #pragma unroll
  for (int n = 0; n < 16; ++n) accS[n] = (f32x4){0.f,0.f,0.f,0.f};

  // ---- QK: 4 key-tiles ----
  #pragma unroll
  for (int kt = 0; kt < 4; ++kt) {
    if (kt < 3) {
      const ushort* kp = kg + (size_t)(kt + 1)*64*256;
      #pragma unroll
      for (int u = 0; u < 8; ++u) rv[u] = *(const uint4*)(kp + u*8);
    } else {
      #pragma unroll
      for (int u = 0; u < 8; ++u) rv[u] = *(const uint4*)(vg + u*8);
    }
    #pragma unroll
    for (int ns = 0; ns < 4; ++ns) {
      #pragma unroll
      for (int dstep = 0; dstep < 8; ++dstep) {
        s16x8 kf = ldfrag(&KV[(ns*16 + lr)*260 + dstep*32 + h*8]);
        accS[kt*4 + ns] = __builtin_amdgcn_mfma_f32_16x16x32_bf16(qf[dstep], kf, accS[kt*4 + ns], 0,0,0);
      }
    }
    __syncthreads();
    if (kt < 3) {
      #pragma unroll
      for (int u = 0; u < 8; ++u) st8(kd + u*8, rv[u]);
    } else {
      #pragma unroll
      for (int u = 0; u < 8; ++u) st8(vd + u*8, rv[u]);   // V-tile 0
    }
    __syncthreads();
  }

  // ---- softmax: fully in-register per wave (rows q = 4h+j, cols spread over lr x 16 regs) ----
  #pragma unroll
  for (int j = 0; j < 4; ++j) {
    float m_ = accS[0][j];
    #pragma unroll
    for (int n = 1; n < 16; ++n) m_ = fmaxf(m_, accS[n][j]);
    #pragma unroll
    for (int msk = 1; msk < 16; msk <<= 1) m_ = fmaxf(m_, __shfl_xor(m_, msk));
    float s_ = 0.f;
    #pragma unroll
    for (int n = 0; n < 16; ++n) {
      float p = __expf(accS[n][j] - m_);
      accS[n][j] = p;
      s_ += p;
    }
    #pragma unroll
    for (int msk = 1; msk < 16; msk <<= 1) s_ += __shfl_xor(s_, msk);
    float ri = 1.f / s_;
    #pragma unroll
    for (int n = 0; n < 16; ++n) accS[n][j] *= ri;
  }

  // ---- PV: 4 key-tiles ----
  // NOTE: Ps is written as ushort and read via ull ldfrag; a __syncthreads()
  // between write and read is REQUIRED (compiler fence — TBAA would otherwise
  // allow reordering the type-punned loads around the stores; round-6 NaN bug).
  f32x4 accO[16];
  #pragma unroll
  for (int n = 0; n < 16; ++n) accO[n] = (f32x4){0.f,0.f,0.f,0.f};

  #pragma unroll
  for (int kt = 0; kt < 4; ++kt) {
    if (kt < 3) {
      const ushort* vp = vg + (kt + 1)*64;
      #pragma unroll
      for (int u = 0; u < 8; ++u) rv[u] = *(const uint4*)(vp + u*8);
    }
    // write own P-subtile
    #pragma unroll
    for (int ns = 0; ns < 4; ++ns)
      #pragma unroll
      for (int j = 0; j < 4; ++j)
        Ps[wid][(4*h + j)*68 + ns*16 + lr] = f2bf(accS[kt*4 + ns][j]);
    __syncthreads();   // fence: Ps stores -> ldfrag loads (and V-tile kt fully read before reuse)
    #pragma unroll
    for (int ks = 0; ks < 2; ++ks) {
      s16x8 pf = ldfrag(&Ps[wid][lr*68 + ks*32 + h*8]);
      #pragma unroll
      for (int ns = 0; ns < 16; ++ns) {
        s16x8 vf = ldfrag(&KV[(ns*16 + lr)*68 + ks*32 + h*8]);
        accO[ns] = __builtin_amdgcn_mfma_f32_16x16x32_bf16(pf, vf, accO[ns], 0,0,0);
      }
    }
    __syncthreads();
    if (kt < 3) {
      #pragma unroll
      for (int u = 0; u < 8; ++u) st8(vd + u*8, rv[u]);
      __syncthreads();
    }
  }

  // ---- epilogue: slab in KV, wide stores ----
  #pragma unroll
  for (int ns = 0; ns < 16; ++ns)
    #pragma unroll
    for (int j = 0; j < 4; ++j)
      KV[(wid*16 + 4*h + j)*260 + ns*16 + lr] = f2bf(accO[ns][j]);
  __syncthreads();
  ushort* aob = AO + (size_t)w*65536;
  #pragma unroll
  for (int it = 0; it < 8; ++it) {
    int task = tid + 256*it;
    int r = task >> 5, seg = task & 31;
    const ushort* sp = &KV[r*260 + seg*8];
    uint4 v;
    ((ull*)&v)[0] = *(const ull*)sp;
    ((ull*)&v)[1] = *(const ull*)(sp + 4);
    *(uint4*)(aob + (size_t)(q0 + r)*256 + seg*8) = v;
  }
}

// ---------------- output projection + residual (register-prefetch staging) ----------------
__global__ __launch_bounds__(512, 2) void k_oproj(const float* __restrict__ x,
    const ushort* __restrict__ AO, const ushort* __restrict__ woE,
    const float* __restrict__ biasAll, float* __restrict__ y) {
  int g = blockIdx.x;
  int w = (g & 7)*128 + (g >> 3);
  int b = w >> 8, wy = (w >> 4) & 15, wx = w & 15;
  int tid = threadIdx.x, l = tid & 63, wid = tid >> 6, h = l >> 4;
  __shared__ __align__(16) ushort alds[256*36];
  __shared__ __align__(16) ushort wlds[256*36];
  const ushort* abase = AO + (size_t)w*65536;

  f32x4 acc[8][4];
  #pragma unroll
  for (int a=0;a<8;a++)
    #pragma unroll
    for (int n=0;n<4;n++) acc[a][n] = (f32x4){0.f,0.f,0.f,0.f};
  int mbase = (wid >> 2)*128, nbase = (wid & 3)*64;

  int orow = tid >> 1, oseg = (tid & 1)*16;
  const ushort* wg0 = woE + (size_t)orow*256 + oseg;
  const ushort* ag0 = abase + (size_t)orow*256 + oseg;
  ushort* wd = &wlds[orow*36 + oseg];
  ushort* ad = &alds[orow*36 + oseg];

  uint4 rw0, rw1, ra0, ra1;
  rw0 = *(const uint4*)(wg0);     rw1 = *(const uint4*)(wg0 + 8);
  ra0 = *(const uint4*)(ag0);     ra1 = *(const uint4*)(ag0 + 8);
  st8(wd, rw0); st8(wd + 8, rw1);
  st8(ad, ra0); st8(ad + 8, ra1);
  __syncthreads();

  for (int ck = 0; ck < 8; ++ck) {
    if (ck < 7) {
      const ushort* wp = wg0 + (ck + 1)*32;
      const ushort* ap2 = ag0 + (ck + 1)*32;
      rw0 = *(const uint4*)(wp);   rw1 = *(const uint4*)(wp + 8);
      ra0 = *(const uint4*)(ap2);  ra1 = *(const uint4*)(ap2 + 8);
    }
    s16x8 bf[4];
    #pragma unroll
    for (int ns = 0; ns < 4; ++ns)
      bf[ns] = ldfrag(&alds[(nbase + ns*16 + (l & 15))*36 + h*8]);
    #pragma unroll
    for (int ms = 0; ms < 8; ++ms) {
      s16x8 af = ldfrag(&wlds[(mbase + ms*16 + (l & 15))*36 + h*8]);
      #pragma unroll
      for (int ns = 0; ns < 4; ++ns)
        acc[ms][ns] = __builtin_amdgcn_mfma_f32_16x16x32_bf16(af, bf[ns], acc[ms][ns], 0,0,0);
    }
    __syncthreads();
    if (ck < 7) {
      st8(wd, rw0); st8(wd + 8, rw1);
      st8(ad, ra0); st8(ad + 8, ra1);
      __syncthreads();
    }
  }
  const float* bs = biasAll + 3072;
  const float* xbase = x + (size_t)b*IMG_ + wy*16*256 + wx*16;
  float* ybase = y + (size_t)b*IMG_ + wy*16*256 + wx*16;
  #pragma unroll
  for (int ms = 0; ms < 8; ++ms) {
    f32x4 b4 = *(const f32x4*)&bs[mbase + ms*16 + 4*h];
    #pragma unroll
    for (int j = 0; j < 4; ++j) {
      int o = mbase + ms*16 + 4*h + j;
      #pragma unroll
      for (int ns = 0; ns < 4; ++ns) {
        int t = nbase + ns*16 + (l & 15);
        size_t off = (size_t)o*HW_ + (t >> 4)*256 + (t & 15);
        ybase[off] = xbase[off] + acc[ms][ns][j] + b4[j];
      }
    }
  }
}

extern "C" void kernel_launch(void* const* d_in, const int* in_sizes, int n_in,
                              void* d_out, int out_size, void* d_ws, size_t ws_size,
                              hipStream_t stream) {
  const float* x     = (const float*)d_in[0];
  const float* gamma = (const float*)d_in[1];
  const float* beta  = (const float*)d_in[2];
  const float* wq = (const float*)d_in[3];
  const float* bq = (const float*)d_in[4];
  const float* wk = (const float*)d_in[5];
  const float* bk = (const float*)d_in[6];
  const float* wv = (const float*)d_in[7];
  const float* bv = (const float*)d_in[8];
  const float* wo = (const float*)d_in[9];
  const float* bo = (const float*)d_in[10];
  float* y = (float*)d_out;
  char* ws = (char*)d_ws;

  float2* part    = (float2*)ws;                        // 8 KB
  float*  biasAll = (float*)(ws + 8192);                // 13.3 KB
  float2* stats   = (float2*)(ws + 24576);              // 1 KB
  ushort* wAll    = (ushort*)(ws + 32768);              // 1.5 MB
  ushort* woE     = (ushort*)(ws + 32768 + 1572864);    // 128 KB
  ushort* Qt      = (ushort*)(ws + 2097152);            // 134 MB (also AO)
  ushort* xnT = (ushort*)d_out;
  ushort* V   = (ushort*)d_out + (size_t)67108864;

  k_stats1<<<1024, 256, 0, stream>>>(x, part);
  k_fold<<<13, 256, 0, stream>>>(wq,bq,wk,bk,wv,bv,wo,bo,gamma,beta,part,wAll,woE,biasAll,stats);
  k_xt<<<1024, 256, 0, stream>>>(x, stats, xnT);

  const size_t KT_SEP_NEED = 2097152ull + 2ull*134217728ull;
  if (ws_size >= KT_SEP_NEED) {
    // enough scratch for a separate Kt -> single proj launch (no in-place hazard)
    ushort* Kt2 = (ushort*)(ws + 2097152 + 134217728);
    k_proj<<<6144, 256, 0, stream>>>(xnT, wAll, biasAll, Qt, Kt2, V, 2);
    k_attn<<<4096, 256, 0, stream>>>(Qt, Kt2, V, Qt /*AO alias: disjoint rows*/);
  } else {
    ushort* Kt = (ushort*)d_out;   // in place over xnT
    k_proj<<<4096, 256, 0, stream>>>(xnT, wAll, biasAll, Qt, Kt, V, 0);  // Q, V
    k_proj<<<2048, 256, 0, stream>>>(xnT, wAll, biasAll, Qt, Kt, V, 1);  // K (in place)
    k_attn<<<4096, 256, 0, stream>>>(Qt, Kt, V, Qt /*AO alias: disjoint rows*/);
  }
  k_oproj<<<1024, 512, 0, stream>>>(x, Qt /*AO*/, woE, biasAll, y);
}